// Round 15
// baseline (71.534 us; speedup 1.0000x reference)
//
#include <hip/hip_runtime.h>

#define NBATCH 16
#define RSZ 128
#define ICH 64
#define OCH 64
#define MODES 16
#define TMODES 32
#define PI2F 6.283185307179586f

typedef float f32x4 __attribute__((ext_vector_type(4)));
typedef short bf16x8 __attribute__((ext_vector_type(8)));

static __device__ __forceinline__ ushort f2bf(float f) {
  union { float f; unsigned u; } v;
  v.f = f;
  unsigned r = v.u + 0x7FFFu + ((v.u >> 16) & 1u);
  return (ushort)(r >> 16);
}
static __device__ __forceinline__ float b2f(ushort u) {
  union { unsigned u; float f; } v;
  v.u = ((unsigned)u) << 16;
  return v.f;
}
// fast HW trig: cos/sin of (2*pi*p/128), p integer
static __device__ __forceinline__ float2 twid(int p) {
  float a = PI2F * (float)p * (1.0f / 128.0f);
  return make_float2(__cosf(a), __sinf(a));
}

// Table sub-offsets inside `tabs` (ushort units)
#define TAB_TM 0            // [32][128]  x-DFT twiddles (MFMA A-operand layout)
#define TAB_EF 4096         // [128][32]
#define TAB_WR 8192         // [64][64]  wrT[o][i]
#define TAB_T1 12288        // [64][256]
#define TAB_E2 28672        // [256][64]

// ---------------- Stage 0: prep (fwT transpose + all twiddle tables) ----------------
__global__ __launch_bounds__(256) void k_prep(const float* __restrict__ fw0,
                                              const float* __restrict__ fw1,
                                              const float* __restrict__ w_res,
                                              ushort* __restrict__ fwT,
                                              ushort* __restrict__ tabs) {
  const int tid = threadIdx.x;
  const int b = blockIdx.x;
  if (b < 128) {
    // fwT[w][t][i][o][c] <- fw{0,1}[i][o][mh][w][c]; block owns (tensor,i), lane owns o
    const int tensor = b >> 6, i = b & 63;
    const float* fw = tensor ? fw1 : fw0;
    const int o = tid & 63, q = tid >> 6;  // q: mh quarter
    const float* src = fw + ((size_t)(i * 64 + o) * 256 + q * 64) * 2;
    ushort2* dst = (ushort2*)fwT;
#pragma unroll 4
    for (int r2 = 0; r2 < 32; ++r2) {
      float4 v = *(const float4*)(src + r2 * 4);
      int r = r2 * 2;
      int mh0 = q * 4 + (r >> 4), w0 = r & 15;
      int mh1 = q * 4 + ((r + 1) >> 4), w1 = (r + 1) & 15;
      int t0 = tensor * 16 + mh0, t1 = tensor * 16 + mh1;
      ushort2 p0, p1;
      p0.x = f2bf(v.x); p0.y = f2bf(v.y);
      p1.x = f2bf(v.z); p1.y = f2bf(v.w);
      dst[(((size_t)w0 * 32 + t0) * 64 + i) * 64 + o] = p0;
      dst[(((size_t)w1 * 32 + t1) * 64 + i) * 64 + o] = p1;
    }
    return;
  }
  __shared__ float2 utp[128];
  if (tid < 128) utp[tid] = twid(tid);
  __syncthreads();
  const int pb = b - 128;
  if (pb == 0) {  // Tm[m=2w+c][x]
    for (int e = tid; e < 4096; e += 256) {
      int m = e >> 7, x = e & 127, w = m >> 1, c = m & 1;
      float2 u = utp[(w * x) & 127];
      tabs[TAB_TM + e] = f2bf(c ? -u.y : u.x);
    }
  } else if (pb == 1) {  // Ef[x][2w+c]
    for (int e = tid; e < 4096; e += 256) {
      int x = e >> 5, mm = e & 31, w = mm >> 1, c = mm & 1;
      float2 u = utp[(w * x) & 127];
      tabs[TAB_EF + e] = f2bf(c ? -u.y : u.x);
    }
  } else if (pb == 2) {  // wrT[o][i]
    for (int e = tid; e < 4096; e += 256) {
      int o = e >> 6, i = e & 63;
      tabs[TAB_WR + e] = f2bf(w_res[i * 64 + o]);
    }
  } else if (pb < 7) {  // T1[64][256]
    for (int k = tid; k < 4096; k += 256) {
      int e = (pb - 3) * 4096 + k;
      int m = e >> 8, kk = e & 255;
      int y = kk & 127, pl = kk >> 7;
      int t = m & 31, imr = m >> 5;
      int h = (t < 16) ? t : (t + 96);
      float2 u = utp[(h * y) & 127];
      float val = (!imr) ? (pl ? u.y : u.x) : (pl ? u.x : -u.y);
      tabs[TAB_T1 + e] = f2bf(val);
    }
  } else {  // pb 7..10: E2[256][64]
    for (int k = tid; k < 4096; k += 256) {
      int e = (pb - 7) * 4096 + k;
      int m = e >> 6, kk = e & 63;
      int y = m & 127, imr = m >> 7;
      int t = kk & 31, pl = kk >> 5;
      int h = (t < 16) ? t : (t + 96);
      float2 u = utp[(h * y) & 127];
      float val = (!imr) ? (pl ? -u.y : u.x) : (pl ? u.x : u.y);
      tabs[TAB_E2 + e] = f2bf(val);
    }
  }
}

// ---------------- Stage 1: x-DFT, 1 row/block, Tm from global tabs, 17.4 KB LDS ----------------
__global__ __launch_bounds__(256) void k_dftx(const float* __restrict__ X,
                                              const ushort* __restrict__ tabs,
                                              ushort* __restrict__ Are,
                                              ushort* __restrict__ Aim) {
  __shared__ ushort XT[64][136];  // 17.4 KB -> 8 blocks/CU (wave-capped)
  const int tid = threadIdx.x;
  const int row = blockIdx.x;
  const float* Xr = X + (size_t)row * RSZ * ICH;
  float4 rv[8];
#pragma unroll
  for (int e = 0; e < 2; ++e) {
    int r = tid + e * 256;
    int i0 = (r & 15) * 4, x0 = (r >> 4) * 4;
    rv[e * 4 + 0] = *(const float4*)&Xr[(x0 + 0) * ICH + i0];
    rv[e * 4 + 1] = *(const float4*)&Xr[(x0 + 1) * ICH + i0];
    rv[e * 4 + 2] = *(const float4*)&Xr[(x0 + 2) * ICH + i0];
    rv[e * 4 + 3] = *(const float4*)&Xr[(x0 + 3) * ICH + i0];
  }
#pragma unroll
  for (int e = 0; e < 2; ++e) {
    int r = tid + e * 256;
    int i0 = (r & 15) * 4, x0 = (r >> 4) * 4;
#pragma unroll
    for (int p = 0; p < 4; ++p) {
      int i = i0 + p;
      int col = x0 ^ ((((i) >> 2) & 7) << 3);
      ushort4 pk;
      pk.x = f2bf(((const float*)&rv[e * 4 + 0])[p]);
      pk.y = f2bf(((const float*)&rv[e * 4 + 1])[p]);
      pk.z = f2bf(((const float*)&rv[e * 4 + 2])[p]);
      pk.w = f2bf(((const float*)&rv[e * 4 + 3])[p]);
      *(ushort4*)&XT[i][col] = pk;
    }
  }
  __syncthreads();
  const int wid = tid >> 6, lane = tid & 63;
  const int lr = lane & 15, lk = lane >> 4;
  f32x4 acc[2];
  acc[0] = (f32x4)(0.f);
  acc[1] = (f32x4)(0.f);
#pragma unroll
  for (int kt = 0; kt < 4; ++kt) {
    int kb = kt * 32 + lk * 8;
    bf16x8 a0 = *(const bf16x8*)&tabs[TAB_TM + lr * 128 + kb];
    bf16x8 a1 = *(const bf16x8*)&tabs[TAB_TM + (16 + lr) * 128 + kb];
    int i = wid * 16 + lr;
    int col = kb ^ (((i >> 2) & 7) << 3);
    bf16x8 b = *(const bf16x8*)&XT[i][col];
    acc[0] = __builtin_amdgcn_mfma_f32_16x16x32_bf16(a0, b, acc[0], 0, 0, 0);
    acc[1] = __builtin_amdgcn_mfma_f32_16x16x32_bf16(a1, b, acc[1], 0, 0, 0);
  }
#pragma unroll
  for (int mt = 0; mt < 2; ++mt)
#pragma unroll
    for (int q = 0; q < 4; ++q) {
      int m = mt * 16 + lk * 4 + q;
      int w = m >> 1, c = m & 1;
      ushort* plane = c ? Aim : Are;
      int i = wid * 16 + lr;
      plane[((size_t)row * MODES + w) * ICH + i] = f2bf(acc[mt][q]);
    }
}

// ---------------- Stage 2 (fused): dfty -> mix -> idfty (R14 verbatim) ----------------
__global__ __launch_bounds__(512) void k_mid(const ushort* __restrict__ Are,
                                             const ushort* __restrict__ Aim,
                                             const ushort* __restrict__ tabs,
                                             const ushort* __restrict__ fwT,
                                             ushort* __restrict__ D) {
  const int n = blockIdx.x >> 4;
  const int w = blockIdx.x & 15;
  __shared__ ushort As[64][264];    // 33.8 KB
  __shared__ float2 Bls[32][66];    // 16.9 KB
  __shared__ ushort Cs[64][72];     // 9.2 KB
  const int tid = threadIdx.x;
#pragma unroll
  for (int e = 0; e < 2; ++e) {
    int tt = e * 512 + tid;
    int pl = tt >> 9, r = tt & 511;
    int i0 = (r & 15) * 4, y0 = (r >> 4) * 4;
    const ushort* P = pl ? Aim : Are;
    const ushort* base = P + (((size_t)(n * RSZ + y0) * MODES + w) * ICH + i0);
    ushort4 r0 = *(const ushort4*)(base + 0 * MODES * ICH);
    ushort4 r1 = *(const ushort4*)(base + 1 * MODES * ICH);
    ushort4 r2 = *(const ushort4*)(base + 2 * MODES * ICH);
    ushort4 r3 = *(const ushort4*)(base + 3 * MODES * ICH);
    const ushort* q0 = (const ushort*)&r0;
    const ushort* q1 = (const ushort*)&r1;
    const ushort* q2 = (const ushort*)&r2;
    const ushort* q3 = (const ushort*)&r3;
#pragma unroll
    for (int p = 0; p < 4; ++p) {
      ushort4 pk;
      pk.x = q0[p]; pk.y = q1[p]; pk.z = q2[p]; pk.w = q3[p];
      *(ushort4*)&As[i0 + p][pl * 128 + y0] = pk;
    }
  }
  __syncthreads();
  const int wid = tid >> 6, lane = tid & 63;
  const int lr = lane & 15, lk = lane >> 4;
  {
    const int mt = wid >> 1, nh = wid & 1;
    f32x4 acc[2];
    acc[0] = (f32x4)(0.f);
    acc[1] = (f32x4)(0.f);
#pragma unroll
    for (int kt = 0; kt < 8; ++kt) {
      int kb = kt * 32 + lk * 8;
      bf16x8 a = *(const bf16x8*)&tabs[TAB_T1 + (mt * 16 + lr) * 256 + kb];
      bf16x8 b0 = *(const bf16x8*)&As[(nh * 2 + 0) * 16 + lr][kb];
      bf16x8 b1 = *(const bf16x8*)&As[(nh * 2 + 1) * 16 + lr][kb];
      acc[0] = __builtin_amdgcn_mfma_f32_16x16x32_bf16(a, b0, acc[0], 0, 0, 0);
      acc[1] = __builtin_amdgcn_mfma_f32_16x16x32_bf16(a, b1, acc[1], 0, 0, 0);
    }
#pragma unroll
    for (int nt2 = 0; nt2 < 2; ++nt2)
#pragma unroll
      for (int q = 0; q < 4; ++q) {
        int m = mt * 16 + lk * 4 + q;
        int t = m & 31, pl = m >> 5;
        int i = (nh * 2 + nt2) * 16 + lr;
        ((float*)&Bls[t][i])[pl] = acc[nt2][q];
      }
  }
  __syncthreads();
  const float sc = (w == 0) ? (1.f / 16384.f) : (2.f / 16384.f);
  float2 cacc[4];
  const ushort2* fwT2 = (const ushort2*)fwT;
#pragma unroll
  for (int p = 0; p < 4; ++p) {
    const int t = p * 8 + wid;
    const ushort2* Wcol = fwT2 + (size_t)(w * 32 + t) * 4096 + lane;
    float cr = 0.f, ci = 0.f;
#pragma unroll 8
    for (int i = 0; i < 64; ++i) {
      ushort2 wv = Wcol[i * 64];
      float wr = b2f(wv.x), wi = b2f(wv.y);
      float2 b = Bls[t][i];
      cr += b.x * wr - b.y * wi;
      ci += b.x * wi + b.y * wr;
    }
    cacc[p] = make_float2(cr * sc, ci * sc);
  }
  __syncthreads();
#pragma unroll
  for (int p = 0; p < 4; ++p) {
    const int t = p * 8 + wid;
    Cs[lane][t] = f2bf(cacc[p].x);
    Cs[lane][t + 32] = f2bf(cacc[p].y);
  }
  __syncthreads();
  f32x4 acc[2][4];
#pragma unroll
  for (int mi = 0; mi < 2; ++mi)
#pragma unroll
    for (int nt = 0; nt < 4; ++nt) acc[mi][nt] = (f32x4)(0.f);
#pragma unroll
  for (int kt = 0; kt < 2; ++kt) {
    int kb = kt * 32 + lk * 8;
    bf16x8 b[4];
#pragma unroll
    for (int nt = 0; nt < 4; ++nt) b[nt] = *(const bf16x8*)&Cs[nt * 16 + lr][kb];
#pragma unroll
    for (int mi = 0; mi < 2; ++mi) {
      bf16x8 a = *(const bf16x8*)&tabs[TAB_E2 + ((wid * 2 + mi) * 16 + lr) * 64 + kb];
#pragma unroll
      for (int nt = 0; nt < 4; ++nt)
        acc[mi][nt] = __builtin_amdgcn_mfma_f32_16x16x32_bf16(a, b[nt], acc[mi][nt], 0, 0, 0);
    }
  }
#pragma unroll
  for (int mi = 0; mi < 2; ++mi)
#pragma unroll
    for (int nt = 0; nt < 4; ++nt)
#pragma unroll
      for (int q = 0; q < 4; ++q) {
        int m = (wid * 2 + mi) * 16 + lk * 4 + q;
        int y = m & 127, pl = m >> 7;
        int o = nt * 16 + lr;
        D[((size_t)(n * RSZ + y) * MODES + w) * 128 + o * 2 + pl] = f2bf(acc[mi][nt][q]);
      }
}

// ---------------- Stage 3: fused [X|E] @ [WresT;Dsc] + bias + SiLU (R14 verbatim) ----------------
__global__ __launch_bounds__(256) void k_final(const float* __restrict__ X,
                                               const ushort* __restrict__ D,
                                               const ushort* __restrict__ tabs,
                                               const float* __restrict__ b_res,
                                               float* __restrict__ out) {
  __shared__ ushort Ac[128][104];
  __shared__ ushort Bc[64][104];
  __shared__ float br[64];
  const int tid = threadIdx.x;
  const int row = blockIdx.x;
  const float* Xr = X + (size_t)row * RSZ * ICH;
#pragma unroll
  for (int j = 0; j < 8; ++j) {
    int k = tid + j * 256;
    int x = k >> 4, i0 = (k & 15) * 4;
    float4 v = *(const float4*)&Xr[x * ICH + i0];
    ushort4 pk;
    pk.x = f2bf(v.x); pk.y = f2bf(v.y); pk.z = f2bf(v.z); pk.w = f2bf(v.w);
    *(ushort4*)&Ac[x][i0] = pk;
  }
  {
    int x = tid >> 1, half = tid & 1;
    *(bf16x8*)&Ac[x][64 + half * 16] = *(const bf16x8*)&tabs[TAB_EF + x * 32 + half * 16];
    *(bf16x8*)&Ac[x][64 + half * 16 + 8] = *(const bf16x8*)&tabs[TAB_EF + x * 32 + half * 16 + 8];
  }
  {
    int o = tid >> 2, s = (tid & 3) * 16;
    *(bf16x8*)&Bc[o][s] = *(const bf16x8*)&tabs[TAB_WR + o * 64 + s];
    *(bf16x8*)&Bc[o][s + 8] = *(const bf16x8*)&tabs[TAB_WR + o * 64 + s + 8];
  }
#pragma unroll
  for (int j = 0; j < 4; ++j) {
    int idx = tid + j * 256;
    int w2 = idx >> 6, o = idx & 63;
    ushort2 v = *(const ushort2*)&D[(size_t)row * 2048 + w2 * 128 + o * 2];
    *(ushort2*)&Bc[o][64 + 2 * w2] = v;
  }
  if (tid < 64) br[tid] = b_res[tid];
  __syncthreads();
  const int wid = tid >> 6, lane = tid & 63;
  const int lr = lane & 15, lk = lane >> 4;
  f32x4 acc[2][4];
#pragma unroll
  for (int mi = 0; mi < 2; ++mi)
#pragma unroll
    for (int nt = 0; nt < 4; ++nt) acc[mi][nt] = (f32x4)(0.f);
#pragma unroll
  for (int kt = 0; kt < 3; ++kt) {
    int kb = kt * 32 + lk * 8;
    bf16x8 a0 = *(const bf16x8*)&Ac[(wid * 2 + 0) * 16 + lr][kb];
    bf16x8 a1 = *(const bf16x8*)&Ac[(wid * 2 + 1) * 16 + lr][kb];
    bf16x8 b[4];
#pragma unroll
    for (int nt = 0; nt < 4; ++nt) b[nt] = *(const bf16x8*)&Bc[nt * 16 + lr][kb];
#pragma unroll
    for (int nt = 0; nt < 4; ++nt) {
      acc[0][nt] = __builtin_amdgcn_mfma_f32_16x16x32_bf16(a0, b[nt], acc[0][nt], 0, 0, 0);
      acc[1][nt] = __builtin_amdgcn_mfma_f32_16x16x32_bf16(a1, b[nt], acc[1][nt], 0, 0, 0);
    }
  }
  float* orow = out + (size_t)row * RSZ * OCH;
#pragma unroll
  for (int mi = 0; mi < 2; ++mi)
#pragma unroll
    for (int nt = 0; nt < 4; ++nt)
#pragma unroll
      for (int q = 0; q < 4; ++q) {
        int x = (wid * 2 + mi) * 16 + lk * 4 + q;
        int o = nt * 16 + lr;
        float v = acc[mi][nt][q] + br[o];
        orow[x * OCH + o] = v / (1.f + __expf(-v));
      }
}

extern "C" void kernel_launch(void* const* d_in, const int* in_sizes, int n_in,
                              void* d_out, int out_size, void* d_ws, size_t ws_size,
                              hipStream_t stream) {
  (void)in_sizes; (void)n_in; (void)out_size; (void)ws_size;
  const float* X = (const float*)d_in[0];
  const float* w_res = (const float*)d_in[1];
  const float* b_res = (const float*)d_in[2];
  const float* fw0 = (const float*)d_in[3];
  const float* fw1 = (const float*)d_in[4];
  float* out = (float*)d_out;
  ushort* wsu = (ushort*)d_ws;
  ushort* Are = wsu;                    // 2,097,152
  ushort* Aim = Are + 2097152;          // 2,097,152
  ushort* Dbf = Aim + 2097152;          // 4,194,304
  ushort* fwT = Dbf + 4194304;          // 4,194,304
  ushort* tabs = fwT + 4194304;         // 45,056
  k_prep<<<139, 256, 0, stream>>>(fw0, fw1, w_res, fwT, tabs);
  k_dftx<<<NBATCH * RSZ, 256, 0, stream>>>(X, tabs, Are, Aim);
  k_mid<<<NBATCH * MODES, 512, 0, stream>>>(Are, Aim, tabs, fwT, Dbf);
  k_final<<<NBATCH * RSZ, 256, 0, stream>>>(X, Dbf, tabs, b_res, out);
}

// Round 16
// 64.878 us; speedup vs baseline: 1.1026x; 1.1026x over previous
//
#include <hip/hip_runtime.h>

#define NBATCH 16
#define RSZ 128
#define ICH 64
#define OCH 64
#define MODES 16
#define TMODES 32
#define PI2F 6.283185307179586f

typedef float f32x4 __attribute__((ext_vector_type(4)));
typedef short bf16x8 __attribute__((ext_vector_type(8)));
typedef unsigned short u16x8 __attribute__((ext_vector_type(8)));

static __device__ __forceinline__ ushort f2bf(float f) {
  union { float f; unsigned u; } v;
  v.f = f;
  unsigned r = v.u + 0x7FFFu + ((v.u >> 16) & 1u);
  return (ushort)(r >> 16);
}
static __device__ __forceinline__ float b2f(ushort u) {
  union { unsigned u; float f; } v;
  v.u = ((unsigned)u) << 16;
  return v.f;
}
// fast HW trig: cos/sin of (2*pi*p/128), p integer
static __device__ __forceinline__ float2 twid(int p) {
  float a = PI2F * (float)p * (1.0f / 128.0f);
  return make_float2(__cosf(a), __sinf(a));
}

// Table sub-offsets inside `tabs` (ushort units)
#define TAB_EF 4096         // [128][32]
#define TAB_WR 8192         // [64][64]  wrT[o][i]
#define TAB_T1 12288        // [64][256]
#define TAB_E2 28672        // [256][64]

#define PREP_BLOCKS 138     // prep blocks FIRST (slow: overlap with dftx bulk)
#define DFTX_BLOCKS 2048    // 1 row per block

// ---------------- Stage 1 (merged): prep blocks first, then dftx blocks ----------------
__global__ __launch_bounds__(256) void k_main(const float* __restrict__ X,
                                              const float* __restrict__ fw0,
                                              const float* __restrict__ fw1,
                                              const float* __restrict__ w_res,
                                              ushort2* __restrict__ A2,
                                              ushort* __restrict__ fwT,
                                              ushort* __restrict__ tabs) {
  const int tid = threadIdx.x;
  if (blockIdx.x < PREP_BLOCKS) {
    const int b = blockIdx.x;
    if (b < 128) {
      // fwT[w][t][i][o][c] <- fw{0,1}[i][o][mh][w][c]; block owns (tensor,i), lane owns o
      const int tensor = b >> 6, i = b & 63;
      const float* fw = tensor ? fw1 : fw0;
      const int o = tid & 63, q = tid >> 6;  // q: mh quarter
      const float* src = fw + ((size_t)(i * 64 + o) * 256 + q * 64) * 2;
      ushort2* dst = (ushort2*)fwT;
#pragma unroll 4
      for (int r2 = 0; r2 < 32; ++r2) {
        float4 v = *(const float4*)(src + r2 * 4);
        int r = r2 * 2;
        int mh0 = q * 4 + (r >> 4), w0 = r & 15;
        int mh1 = q * 4 + ((r + 1) >> 4), w1 = (r + 1) & 15;
        int t0 = tensor * 16 + mh0, t1 = tensor * 16 + mh1;
        ushort2 p0, p1;
        p0.x = f2bf(v.x); p0.y = f2bf(v.y);
        p1.x = f2bf(v.z); p1.y = f2bf(v.w);
        dst[(((size_t)w0 * 32 + t0) * 64 + i) * 64 + o] = p0;
        dst[(((size_t)w1 * 32 + t1) * 64 + i) * 64 + o] = p1;
      }
      return;
    }
    __shared__ float2 utp[128];
    if (tid < 128) utp[tid] = twid(tid);
    __syncthreads();
    const int pb = b - 128;
    if (pb == 0) {  // Ef[x][2w+c]
      for (int e = tid; e < 4096; e += 256) {
        int x = e >> 5, mm = e & 31, w = mm >> 1, c = mm & 1;
        float2 u = utp[(w * x) & 127];
        tabs[TAB_EF + e] = f2bf(c ? -u.y : u.x);
      }
    } else if (pb == 1) {  // wrT[o][i]
      for (int e = tid; e < 4096; e += 256) {
        int o = e >> 6, i = e & 63;
        tabs[TAB_WR + e] = f2bf(w_res[i * 64 + o]);
      }
    } else if (pb < 6) {  // T1[64][256]
      for (int k = tid; k < 4096; k += 256) {
        int e = (pb - 2) * 4096 + k;
        int m = e >> 8, kk = e & 255;
        int y = kk & 127, pl = kk >> 7;
        int t = m & 31, imr = m >> 5;
        int h = (t < 16) ? t : (t + 96);
        float2 u = utp[(h * y) & 127];
        float val = (!imr) ? (pl ? u.y : u.x) : (pl ? u.x : -u.y);
        tabs[TAB_T1 + e] = f2bf(val);
      }
    } else {  // pb 6..9: E2[256][64]
      for (int k = tid; k < 4096; k += 256) {
        int e = (pb - 6) * 4096 + k;
        int m = e >> 6, kk = e & 63;
        int y = m & 127, imr = m >> 7;
        int t = kk & 31, pl = kk >> 5;
        int h = (t < 16) ? t : (t + 96);
        float2 u = utp[(h * y) & 127];
        float val = (!imr) ? (pl ? -u.y : u.x) : (pl ? u.x : u.y);
        tabs[TAB_E2 + e] = f2bf(val);
      }
    }
    return;
  }
  // ---- dftx: 1 row per block, ~27 KB LDS ----
  __shared__ float2 ut[128];
  __shared__ ushort Tm[32][136];
  __shared__ ushort XT[64][136];
  const int row = blockIdx.x - PREP_BLOCKS;
  const float* Xr = X + (size_t)row * RSZ * ICH;
  // issue X loads early (latency overlaps twiddle phase + barrier)
  float4 rv[8];
#pragma unroll
  for (int e = 0; e < 2; ++e) {
    int r = tid + e * 256;
    int i0 = (r & 15) * 4, x0 = (r >> 4) * 4;
    rv[e * 4 + 0] = *(const float4*)&Xr[(x0 + 0) * ICH + i0];
    rv[e * 4 + 1] = *(const float4*)&Xr[(x0 + 1) * ICH + i0];
    rv[e * 4 + 2] = *(const float4*)&Xr[(x0 + 2) * ICH + i0];
    rv[e * 4 + 3] = *(const float4*)&Xr[(x0 + 3) * ICH + i0];
  }
  if (tid < 128) ut[tid] = twid(tid);
  __syncthreads();
  // Tm[m=2w+c][x] from ut
#pragma unroll
  for (int e = 0; e < 16; ++e) {
    int idx = tid + e * 256;
    int m = idx >> 7, x = idx & 127;
    int w = m >> 1, c = m & 1;
    float2 u = ut[(w * x) & 127];
    Tm[m][x] = f2bf(c ? -u.y : u.x);
  }
  // XT from registers
#pragma unroll
  for (int e = 0; e < 2; ++e) {
    int r = tid + e * 256;
    int i0 = (r & 15) * 4, x0 = (r >> 4) * 4;
#pragma unroll
    for (int p = 0; p < 4; ++p) {
      int i = i0 + p;
      int col = x0 ^ ((((i) >> 2) & 7) << 3);
      ushort4 pk;
      pk.x = f2bf(((const float*)&rv[e * 4 + 0])[p]);
      pk.y = f2bf(((const float*)&rv[e * 4 + 1])[p]);
      pk.z = f2bf(((const float*)&rv[e * 4 + 2])[p]);
      pk.w = f2bf(((const float*)&rv[e * 4 + 3])[p]);
      *(ushort4*)&XT[i][col] = pk;
    }
  }
  __syncthreads();
  const int wid = tid >> 6, lane = tid & 63;
  const int lr = lane & 15, lk = lane >> 4;
  f32x4 acc[2];
  acc[0] = (f32x4)(0.f);
  acc[1] = (f32x4)(0.f);
#pragma unroll
  for (int kt = 0; kt < 4; ++kt) {
    int kb = kt * 32 + lk * 8;
    bf16x8 a0 = *(const bf16x8*)&Tm[lr][kb];
    bf16x8 a1 = *(const bf16x8*)&Tm[16 + lr][kb];
    int i = wid * 16 + lr;
    int col = kb ^ (((i >> 2) & 7) << 3);
    bf16x8 b = *(const bf16x8*)&XT[i][col];
    acc[0] = __builtin_amdgcn_mfma_f32_16x16x32_bf16(a0, b, acc[0], 0, 0, 0);
    acc[1] = __builtin_amdgcn_mfma_f32_16x16x32_bf16(a1, b, acc[1], 0, 0, 0);
  }
  // packed complex stores: per instruction, 16 lanes x ushort2 = full 64B lines
  {
    const int i = wid * 16 + lr;
#pragma unroll
    for (int mt = 0; mt < 2; ++mt) {
      int wb = mt * 8 + lk * 2;  // m = mt*16+lk*4+q -> w = m>>1, c = m&1
      ushort2 p0, p1;
      p0.x = f2bf(acc[mt][0]); p0.y = f2bf(acc[mt][1]);  // w = wb
      p1.x = f2bf(acc[mt][2]); p1.y = f2bf(acc[mt][3]);  // w = wb+1
      A2[((size_t)row * MODES + wb) * ICH + i] = p0;
      A2[((size_t)row * MODES + wb + 1) * ICH + i] = p1;
    }
  }
}

// ---------------- Stage 2 (fused): dfty -> mix -> idfty ----------------
__global__ __launch_bounds__(512) void k_mid(const ushort2* __restrict__ A2,
                                             const ushort* __restrict__ tabs,
                                             const ushort* __restrict__ fwT,
                                             ushort* __restrict__ D) {
  const int n = blockIdx.x >> 4;
  const int w = blockIdx.x & 15;
  __shared__ ushort As[64][264];    // 33.8 KB  [i][y + 128*pl]
  __shared__ float2 Bls[32][66];    // 16.9 KB (fp32 B-stack)
  __shared__ ushort Cs[64][72];     // 9.2 KB
  const int tid = threadIdx.x;
  // stage A-slice: 16B interleaved loads, register transpose to re/im planes
  {
    const int i0 = (tid & 15) * 4, y0 = (tid >> 4) * 4;  // tid>>4 in 0..31 -> y0 0..124
    u16x8 vy[4];
#pragma unroll
    for (int dy = 0; dy < 4; ++dy)
      vy[dy] = *(const u16x8*)&A2[((size_t)(n * RSZ + y0 + dy) * MODES + w) * ICH + i0];
#pragma unroll
    for (int p = 0; p < 4; ++p) {
      ushort4 re, im;
      re.x = vy[0][2 * p];     re.y = vy[1][2 * p];     re.z = vy[2][2 * p];     re.w = vy[3][2 * p];
      im.x = vy[0][2 * p + 1]; im.y = vy[1][2 * p + 1]; im.z = vy[2][2 * p + 1]; im.w = vy[3][2 * p + 1];
      *(ushort4*)&As[i0 + p][y0] = re;
      *(ushort4*)&As[i0 + p][128 + y0] = im;
    }
  }
  __syncthreads();
  const int wid = tid >> 6, lane = tid & 63;
  const int lr = lane & 15, lk = lane >> 4;
  // ---- dfty MFMA: Bstack(64x64) = T1(64x256) @ As(256x64) -> LDS fp32; T1 from global ----
  {
    const int mt = wid >> 1, nh = wid & 1;
    f32x4 acc[2];
    acc[0] = (f32x4)(0.f);
    acc[1] = (f32x4)(0.f);
#pragma unroll
    for (int kt = 0; kt < 8; ++kt) {
      int kb = kt * 32 + lk * 8;
      bf16x8 a = *(const bf16x8*)&tabs[TAB_T1 + (mt * 16 + lr) * 256 + kb];
      bf16x8 b0 = *(const bf16x8*)&As[(nh * 2 + 0) * 16 + lr][kb];
      bf16x8 b1 = *(const bf16x8*)&As[(nh * 2 + 1) * 16 + lr][kb];
      acc[0] = __builtin_amdgcn_mfma_f32_16x16x32_bf16(a, b0, acc[0], 0, 0, 0);
      acc[1] = __builtin_amdgcn_mfma_f32_16x16x32_bf16(a, b1, acc[1], 0, 0, 0);
    }
#pragma unroll
    for (int nt2 = 0; nt2 < 2; ++nt2)
#pragma unroll
      for (int q = 0; q < 4; ++q) {
        int m = mt * 16 + lk * 4 + q;
        int t = m & 31, pl = m >> 5;
        int i = (nh * 2 + nt2) * 16 + lr;
        ((float*)&Bls[t][i])[pl] = acc[nt2][q];
      }
  }
  __syncthreads();
  // ---- mix: C[t][o] = sum_i B[t][i]*W[t][i][o]; wave = t, lane = o ----
  const float sc = (w == 0) ? (1.f / 16384.f) : (2.f / 16384.f);
  float2 cacc[4];
  const ushort2* fwT2 = (const ushort2*)fwT;
#pragma unroll
  for (int p = 0; p < 4; ++p) {
    const int t = p * 8 + wid;
    const ushort2* Wcol = fwT2 + (size_t)(w * 32 + t) * 4096 + lane;
    float cr = 0.f, ci = 0.f;
#pragma unroll 8
    for (int i = 0; i < 64; ++i) {
      ushort2 wv = Wcol[i * 64];
      float wr = b2f(wv.x), wi = b2f(wv.y);
      float2 b = Bls[t][i];
      cr += b.x * wr - b.y * wi;
      ci += b.x * wi + b.y * wr;
    }
    cacc[p] = make_float2(cr * sc, ci * sc);
  }
  __syncthreads();
#pragma unroll
  for (int p = 0; p < 4; ++p) {
    const int t = p * 8 + wid;
    Cs[lane][t] = f2bf(cacc[p].x);
    Cs[lane][t + 32] = f2bf(cacc[p].y);
  }
  __syncthreads();
  // ---- idfty MFMA: Dstack(256x64) = E2(256x64) @ Cs(64x64); E2 from global ----
  f32x4 acc[2][4];
#pragma unroll
  for (int mi = 0; mi < 2; ++mi)
#pragma unroll
    for (int nt = 0; nt < 4; ++nt) acc[mi][nt] = (f32x4)(0.f);
#pragma unroll
  for (int kt = 0; kt < 2; ++kt) {
    int kb = kt * 32 + lk * 8;
    bf16x8 b[4];
#pragma unroll
    for (int nt = 0; nt < 4; ++nt) b[nt] = *(const bf16x8*)&Cs[nt * 16 + lr][kb];
#pragma unroll
    for (int mi = 0; mi < 2; ++mi) {
      bf16x8 a = *(const bf16x8*)&tabs[TAB_E2 + ((wid * 2 + mi) * 16 + lr) * 64 + kb];
#pragma unroll
      for (int nt = 0; nt < 4; ++nt)
        acc[mi][nt] = __builtin_amdgcn_mfma_f32_16x16x32_bf16(a, b[nt], acc[mi][nt], 0, 0, 0);
    }
  }
#pragma unroll
  for (int mi = 0; mi < 2; ++mi)
#pragma unroll
    for (int nt = 0; nt < 4; ++nt)
#pragma unroll
      for (int q = 0; q < 4; ++q) {
        int m = (wid * 2 + mi) * 16 + lk * 4 + q;
        int y = m & 127, pl = m >> 7;
        int o = nt * 16 + lr;
        D[((size_t)(n * RSZ + y) * MODES + w) * 128 + o * 2 + pl] = f2bf(acc[mi][nt][q]);
      }
}

// ---------------- Stage 3: fused [X|E] @ [WresT;Dsc] + bias + SiLU ----------------
__global__ __launch_bounds__(256) void k_final(const float* __restrict__ X,
                                               const ushort* __restrict__ D,
                                               const ushort* __restrict__ tabs,
                                               const float* __restrict__ b_res,
                                               float* __restrict__ out) {
  __shared__ ushort Ac[128][104];
  __shared__ ushort Bc[64][104];
  __shared__ float br[64];
  const int tid = threadIdx.x;
  const int row = blockIdx.x;
  const float* Xr = X + (size_t)row * RSZ * ICH;
#pragma unroll
  for (int j = 0; j < 8; ++j) {
    int k = tid + j * 256;
    int x = k >> 4, i0 = (k & 15) * 4;
    float4 v = *(const float4*)&Xr[x * ICH + i0];
    ushort4 pk;
    pk.x = f2bf(v.x); pk.y = f2bf(v.y); pk.z = f2bf(v.z); pk.w = f2bf(v.w);
    *(ushort4*)&Ac[x][i0] = pk;
  }
  {
    int x = tid >> 1, half = tid & 1;
    *(bf16x8*)&Ac[x][64 + half * 16] = *(const bf16x8*)&tabs[TAB_EF + x * 32 + half * 16];
    *(bf16x8*)&Ac[x][64 + half * 16 + 8] = *(const bf16x8*)&tabs[TAB_EF + x * 32 + half * 16 + 8];
  }
  {
    int o = tid >> 2, s = (tid & 3) * 16;
    *(bf16x8*)&Bc[o][s] = *(const bf16x8*)&tabs[TAB_WR + o * 64 + s];
    *(bf16x8*)&Bc[o][s + 8] = *(const bf16x8*)&tabs[TAB_WR + o * 64 + s + 8];
  }
#pragma unroll
  for (int j = 0; j < 4; ++j) {
    int idx = tid + j * 256;
    int w2 = idx >> 6, o = idx & 63;
    ushort2 v = *(const ushort2*)&D[(size_t)row * 2048 + w2 * 128 + o * 2];
    *(ushort2*)&Bc[o][64 + 2 * w2] = v;
  }
  if (tid < 64) br[tid] = b_res[tid];
  __syncthreads();
  const int wid = tid >> 6, lane = tid & 63;
  const int lr = lane & 15, lk = lane >> 4;
  f32x4 acc[2][4];
#pragma unroll
  for (int mi = 0; mi < 2; ++mi)
#pragma unroll
    for (int nt = 0; nt < 4; ++nt) acc[mi][nt] = (f32x4)(0.f);
#pragma unroll
  for (int kt = 0; kt < 3; ++kt) {
    int kb = kt * 32 + lk * 8;
    bf16x8 a0 = *(const bf16x8*)&Ac[(wid * 2 + 0) * 16 + lr][kb];
    bf16x8 a1 = *(const bf16x8*)&Ac[(wid * 2 + 1) * 16 + lr][kb];
    bf16x8 b[4];
#pragma unroll
    for (int nt = 0; nt < 4; ++nt) b[nt] = *(const bf16x8*)&Bc[nt * 16 + lr][kb];
#pragma unroll
    for (int nt = 0; nt < 4; ++nt) {
      acc[0][nt] = __builtin_amdgcn_mfma_f32_16x16x32_bf16(a0, b[nt], acc[0][nt], 0, 0, 0);
      acc[1][nt] = __builtin_amdgcn_mfma_f32_16x16x32_bf16(a1, b[nt], acc[1][nt], 0, 0, 0);
    }
  }
  float* orow = out + (size_t)row * RSZ * OCH;
#pragma unroll
  for (int mi = 0; mi < 2; ++mi)
#pragma unroll
    for (int nt = 0; nt < 4; ++nt)
#pragma unroll
      for (int q = 0; q < 4; ++q) {
        int x = (wid * 2 + mi) * 16 + lk * 4 + q;
        int o = nt * 16 + lr;
        float v = acc[mi][nt][q] + br[o];
        orow[x * OCH + o] = v / (1.f + __expf(-v));
      }
}

extern "C" void kernel_launch(void* const* d_in, const int* in_sizes, int n_in,
                              void* d_out, int out_size, void* d_ws, size_t ws_size,
                              hipStream_t stream) {
  (void)in_sizes; (void)n_in; (void)out_size; (void)ws_size;
  const float* X = (const float*)d_in[0];
  const float* w_res = (const float*)d_in[1];
  const float* b_res = (const float*)d_in[2];
  const float* fw0 = (const float*)d_in[3];
  const float* fw1 = (const float*)d_in[4];
  float* out = (float*)d_out;
  ushort* wsu = (ushort*)d_ws;
  ushort2* A2 = (ushort2*)wsu;          // 2,097,152 ushort2 = 4,194,304 ushorts
  ushort* Dbf = wsu + 4194304;          // 4,194,304
  ushort* fwT = Dbf + 4194304;          // 4,194,304
  ushort* tabs = fwT + 4194304;         // 45,056
  k_main<<<PREP_BLOCKS + DFTX_BLOCKS, 256, 0, stream>>>(X, fw0, fw1, w_res, A2, fwT, tabs);
  k_mid<<<NBATCH * MODES, 512, 0, stream>>>(A2, tabs, fwT, Dbf);
  k_final<<<NBATCH * RSZ, 256, 0, stream>>>(X, Dbf, tabs, b_res, out);
}